// Round 1
// baseline (176.741 us; speedup 1.0000x reference)
//
#include <hip/hip_runtime.h>
#include <float.h>

// Problem constants: B=32, C=256, HW=1024, K=1024, L=64
// d_out = [ out: 32*256*1024 = 8388608 floats ][ nearest: 32*1024*64 = 2097152 floats ]
//
// Workspace layout (floats):
//   wT   [256*64]  @ 0      : wT[c*64+l]   = W_in[l*256+c]
//   woT  [64*256]  @ 16384  : woT[l*256+c] = W_out[c*64+l]
//   cbT  [64*1024] @ 32768  : cbT[l*1024+k]= cb[k*64+l]
//   cbn  [1024]    @ 98304  : ||cb_k||^2

__global__ void prep_kernel(const float* __restrict__ Win,
                            const float* __restrict__ Wout,
                            const float* __restrict__ cb,
                            float* __restrict__ ws) {
    int gid = blockIdx.x * 256 + threadIdx.x;
    if (gid < 16384) {
        int c = gid >> 6, l = gid & 63;
        ws[gid] = Win[l * 256 + c];
    } else if (gid < 32768) {
        int i = gid - 16384;
        int l = i >> 8, c = i & 255;
        ws[gid] = Wout[c * 64 + l];
    } else if (gid < 98304) {
        int i = gid - 32768;
        int l = i >> 10, k = i & 1023;
        ws[gid] = cb[k * 64 + l];
    } else if (gid < 99328) {
        int k = gid - 98304;
        const float* r = cb + k * 64;
        float s = 0.f;
        #pragma unroll 16
        for (int l = 0; l < 64; l++) s += r[l] * r[l];
        ws[gid] = s;
    }
}

#define FMA4(A, SC, V) \
    { (A).x += (SC) * (V).x; (A).y += (SC) * (V).y; (A).z += (SC) * (V).z; (A).w += (SC) * (V).w; }

__launch_bounds__(256, 2)
__global__ void vq_kernel(const float* __restrict__ x,
                          const float* __restrict__ cb,
                          const float* __restrict__ b_in,
                          const float* __restrict__ b_out,
                          const float* __restrict__ ws,
                          float* __restrict__ out) {
    // LDS: 16K (zT / nrT) + 32K (staging union) + small = ~58 KB -> 2 blocks/CU
    __shared__ float4 s_zT[64 * 16];    // zT[l][s] 64x64 floats; later reused as nrT[l][s]
    __shared__ float4 s_buf[64 * 32];   // phase1: xs(1024 f4)+wTs(1024 f4); phase2: cb chunk; phase3: woT chunk
    __shared__ float  s_cbn[128];
    __shared__ float  s_rd[64 * 17];
    __shared__ int    s_rk[64 * 17];
    __shared__ int    s_ks[64];

    const int t  = threadIdx.x;
    const int b  = blockIdx.x >> 4;
    const int s0 = (blockIdx.x & 15) << 6;

    const float4* wT4  = (const float4*)(ws);           // [256][16] f4
    const float4* woT4 = (const float4*)(ws + 16384);   // [64][64] f4
    const float4* cbT4 = (const float4*)(ws + 32768);   // [64][256] f4
    const float*  cbn  = ws + 98304;
    const float4* x4   = (const float4*)x;
    const float4* cb4  = (const float4*)cb;
    float* zTs = (float*)s_zT;

    const int sgrp = t & 15;   // s quad: s = sgrp*4 + i
    const int lgrp = t >> 4;   // l quad (phase1) / k group (phase2)

    // ---------------- phase 1: zT[l][s] = W_in @ x_tile + b_in ----------------
    float4 acc1[4];
    {
        #pragma unroll
        for (int a = 0; a < 4; a++) {
            float bi = b_in[lgrp * 4 + a];
            acc1[a].x = bi; acc1[a].y = bi; acc1[a].z = bi; acc1[a].w = bi;
        }
    }
    for (int cc = 0; cc < 4; cc++) {
        __syncthreads();
        #pragma unroll
        for (int i = 0; i < 4; i++) {
            int idx = i * 256 + t;
            int c = idx >> 4, colq = idx & 15;
            s_buf[idx]        = x4[(b * 256 + cc * 64 + c) * 256 + (s0 >> 2) + colq];
            s_buf[1024 + idx] = wT4[(cc * 64 + c) * 16 + colq];
        }
        __syncthreads();
        #pragma unroll 8
        for (int c = 0; c < 64; c++) {
            float4 wv = s_buf[1024 + c * 16 + lgrp];
            float4 xv = s_buf[c * 16 + sgrp];
            FMA4(acc1[0], wv.x, xv);
            FMA4(acc1[1], wv.y, xv);
            FMA4(acc1[2], wv.z, xv);
            FMA4(acc1[3], wv.w, xv);
        }
    }
    #pragma unroll
    for (int a = 0; a < 4; a++) {
        s_zT[(lgrp * 4 + a) * 16 + sgrp] = acc1[a];
    }
    // (sync happens at top of phase-2 chunk loop before s_buf reuse / zT read)

    // ---------------- phase 2: d[s][k] = ||cb_k||^2 - 2 z_s . cb_k ; argmin ----------------
    const int kgrp = lgrp;     // 16 groups x 8 k per 128-chunk
    float dmin0 = FLT_MAX, dmin1 = FLT_MAX, dmin2 = FLT_MAX, dmin3 = FLT_MAX;
    int   kmin0 = 0, kmin1 = 0, kmin2 = 0, kmin3 = 0;

    for (int kc = 0; kc < 8; kc++) {
        __syncthreads();
        #pragma unroll
        for (int i = 0; i < 8; i++) {
            int idx = i * 256 + t;          // 0..2047
            int l = idx >> 5, col = idx & 31;
            s_buf[idx] = cbT4[l * 256 + kc * 32 + col];
        }
        if (t < 32) ((float4*)s_cbn)[t] = ((const float4*)(cbn + kc * 128))[t];
        __syncthreads();

        float4 acc2[8];
        #pragma unroll
        for (int j = 0; j < 8; j++) { acc2[j].x = 0.f; acc2[j].y = 0.f; acc2[j].z = 0.f; acc2[j].w = 0.f; }

        #pragma unroll 8
        for (int l = 0; l < 64; l++) {
            float4 zv = s_zT[l * 16 + sgrp];
            float4 c0 = s_buf[l * 32 + kgrp * 2];
            float4 c1 = s_buf[l * 32 + kgrp * 2 + 1];
            FMA4(acc2[0], c0.x, zv);
            FMA4(acc2[1], c0.y, zv);
            FMA4(acc2[2], c0.z, zv);
            FMA4(acc2[3], c0.w, zv);
            FMA4(acc2[4], c1.x, zv);
            FMA4(acc2[5], c1.y, zv);
            FMA4(acc2[6], c1.z, zv);
            FMA4(acc2[7], c1.w, zv);
        }
        #pragma unroll
        for (int j = 0; j < 8; j++) {
            int   k  = kc * 128 + kgrp * 8 + j;
            float cn = s_cbn[kgrp * 8 + j];
            float d0 = cn - 2.f * acc2[j].x;
            float d1 = cn - 2.f * acc2[j].y;
            float d2 = cn - 2.f * acc2[j].z;
            float d3 = cn - 2.f * acc2[j].w;
            if (d0 < dmin0) { dmin0 = d0; kmin0 = k; }
            if (d1 < dmin1) { dmin1 = d1; kmin1 = k; }
            if (d2 < dmin2) { dmin2 = d2; kmin2 = k; }
            if (d3 < dmin3) { dmin3 = d3; kmin3 = k; }
        }
    }

    // cross-thread argmin reduce (16 kgrps per position), tie-break on lower k
    {
        int s = sgrp * 4;
        s_rd[(s + 0) * 17 + kgrp] = dmin0;  s_rk[(s + 0) * 17 + kgrp] = kmin0;
        s_rd[(s + 1) * 17 + kgrp] = dmin1;  s_rk[(s + 1) * 17 + kgrp] = kmin1;
        s_rd[(s + 2) * 17 + kgrp] = dmin2;  s_rk[(s + 2) * 17 + kgrp] = kmin2;
        s_rd[(s + 3) * 17 + kgrp] = dmin3;  s_rk[(s + 3) * 17 + kgrp] = kmin3;
    }
    __syncthreads();
    if (t < 64) {
        float best = s_rd[t * 17];
        int   bk   = s_rk[t * 17];
        #pragma unroll
        for (int j = 1; j < 16; j++) {
            float d = s_rd[t * 17 + j];
            int   k = s_rk[t * 17 + j];
            if (d < best || (d == best && k < bk)) { best = d; bk = k; }
        }
        s_ks[t] = bk;
    }
    __syncthreads();

    // ---------------- gather nearest = cb[idx] ----------------
    // (a) coalesced float4 write of nearest [s][l] to d_out tail
    float4* nearest4 = (float4*)(out + 8388608);
    #pragma unroll
    for (int i = 0; i < 4; i++) {
        int idx = i * 256 + t;
        int s = idx >> 4, lq = idx & 15;
        nearest4[(b * 1024 + s0 + s) * 16 + lq] = cb4[s_ks[s] * 16 + lq];
    }
    // (b) build nrT[l][s] in s_zT (lane = s -> conflict-free LDS writes)
    {
        int s = t & 63, wq = t >> 6;
        #pragma unroll
        for (int j = 0; j < 16; j++) {
            int l = wq * 16 + j;
            zTs[l * 64 + s] = cb[s_ks[s] * 64 + l];
        }
    }
    // (sync at top of phase-3 chunk loop covers these writes)

    // ---------------- phase 3: out[c][s] = W_out @ nearest + b_out ----------------
    const int cgrp = t >> 3;   // 0..31 -> 4 c each (per 128-chunk)
    const int sg3  = t & 7;    // 0..7  -> 8 s each
    for (int cc = 0; cc < 2; cc++) {
        __syncthreads();
        #pragma unroll
        for (int i = 0; i < 8; i++) {
            int idx = i * 256 + t;
            int l = idx >> 5, col = idx & 31;
            s_buf[idx] = woT4[l * 64 + cc * 32 + col];
        }
        __syncthreads();

        float4 accA[4], accB[4];
        #pragma unroll
        for (int a = 0; a < 4; a++) {
            accA[a].x = 0.f; accA[a].y = 0.f; accA[a].z = 0.f; accA[a].w = 0.f;
            accB[a].x = 0.f; accB[a].y = 0.f; accB[a].z = 0.f; accB[a].w = 0.f;
        }
        #pragma unroll 8
        for (int l = 0; l < 64; l++) {
            float4 wv = s_buf[l * 32 + cgrp];
            float4 n0 = s_zT[l * 16 + sg3 * 2];
            float4 n1 = s_zT[l * 16 + sg3 * 2 + 1];
            FMA4(accA[0], wv.x, n0); FMA4(accB[0], wv.x, n1);
            FMA4(accA[1], wv.y, n0); FMA4(accB[1], wv.y, n1);
            FMA4(accA[2], wv.z, n0); FMA4(accB[2], wv.z, n1);
            FMA4(accA[3], wv.w, n0); FMA4(accB[3], wv.w, n1);
        }
        #pragma unroll
        for (int a = 0; a < 4; a++) {
            int c = cc * 128 + cgrp * 4 + a;
            float bo = b_out[c];
            float4 o0, o1;
            o0.x = accA[a].x + bo; o0.y = accA[a].y + bo; o0.z = accA[a].z + bo; o0.w = accA[a].w + bo;
            o1.x = accB[a].x + bo; o1.y = accB[a].y + bo; o1.z = accB[a].z + bo; o1.w = accB[a].w + bo;
            float4* op = (float4*)(out + (b * 256 + c) * 1024 + s0 + sg3 * 8);
            op[0] = o0;
            op[1] = o1;
        }
    }
}

extern "C" void kernel_launch(void* const* d_in, const int* in_sizes, int n_in,
                              void* d_out, int out_size, void* d_ws, size_t ws_size,
                              hipStream_t stream) {
    const float* x    = (const float*)d_in[0];
    const float* cb   = (const float*)d_in[1];
    const float* Win  = (const float*)d_in[2];
    const float* bin  = (const float*)d_in[3];
    const float* Wout = (const float*)d_in[4];
    const float* bout = (const float*)d_in[5];
    float* out = (float*)d_out;
    float* ws  = (float*)d_ws;

    prep_kernel<<<388, 256, 0, stream>>>(Win, Wout, cb, ws);
    vq_kernel<<<512, 256, 0, stream>>>(x, cb, bin, bout, ws, out);
}

// Round 2
// 150.731 us; speedup vs baseline: 1.1726x; 1.1726x over previous
//
#include <hip/hip_runtime.h>
#include <float.h>

// B=32, C=256, HW=1024 (16 s-tiles of 64), K=1024, L=64
// d_out = [ out: 8388608 f32 ][ nearest: 2097152 f32 ]
//
// ws layout (float units):
//   wT   [256*64] @ 0      : wT[c*64+l] = W_in[l*256+c]           (fp32)
//   cbn  [1024]   @ 16384  : ||cb_k||^2                           (fp32)
//   cbh  [1024*64] ushort @ float-ofs 17408  (bf16 hi of cb)
//   cbl  [1024*64] ushort  (bf16 lo)
//   wouth[256*64]  ushort  (bf16 hi of W_out)
//   woutl[256*64]  ushort  (bf16 lo)

typedef __attribute__((ext_vector_type(8))) short short8v;
typedef __attribute__((ext_vector_type(4))) float f32x4;

#define MFMA16(A, B, C) __builtin_amdgcn_mfma_f32_16x16x32_bf16((A), (B), (C), 0, 0, 0)

__device__ __forceinline__ unsigned short f2bf(float f) {
    unsigned int u = __float_as_uint(f);
    u += 0x7FFFu + ((u >> 16) & 1u);
    return (unsigned short)(u >> 16);
}
__device__ __forceinline__ float bf2f(unsigned short h) {
    return __uint_as_float(((unsigned int)h) << 16);
}

__global__ void prep_kernel(const float* __restrict__ Win,
                            const float* __restrict__ Wout,
                            const float* __restrict__ cb,
                            float* __restrict__ ws) {
    __shared__ float tile[64][65];
    unsigned short* cbh   = (unsigned short*)(ws + 17408);
    unsigned short* cbl   = cbh + 65536;
    unsigned short* wouth = cbl + 65536;
    unsigned short* woutl = wouth + 16384;
    float* cbn = ws + 16384;
    float* wT  = ws;
    const int blk = blockIdx.x, t = threadIdx.x;

    if (blk < 256) {
        // codebook bf16 split + ||cb||^2 (one wave per code row: 64 lanes = 64 dims)
        int gid = blk * 256 + t;
        float v = cb[gid];
        unsigned short h = f2bf(v);
        cbh[gid] = h;
        cbl[gid] = f2bf(v - bf2f(h));
        float sq = v * v;
        #pragma unroll
        for (int m = 1; m < 64; m <<= 1) sq += __shfl_xor(sq, m);
        if ((t & 63) == 0) cbn[gid >> 6] = sq;
    } else if (blk < 320) {
        int gid = (blk - 256) * 256 + t;
        float v = Wout[gid];
        unsigned short h = f2bf(v);
        wouth[gid] = h;
        woutl[gid] = f2bf(v - bf2f(h));
    } else {
        // W_in transpose via LDS tile (coalesced both ways)
        int c0 = (blk - 320) * 64;
        #pragma unroll
        for (int it = 0; it < 16; it++) {
            int idx = it * 256 + t;
            int l = idx >> 6, c = idx & 63;
            tile[l][c] = Win[l * 256 + c0 + c];
        }
        __syncthreads();
        #pragma unroll
        for (int it = 0; it < 16; it++) {
            int idx = it * 256 + t;
            int c = idx >> 6, l = idx & 63;
            wT[(c0 + c) * 64 + l] = tile[l][c];
        }
    }
}

__launch_bounds__(256, 2)
__global__ void vq_kernel(const float* __restrict__ x,
                          const float* __restrict__ cb,
                          const float* __restrict__ b_in,
                          const float* __restrict__ b_out,
                          const float* __restrict__ ws,
                          float* __restrict__ out) {
    __shared__ __align__(16) float s_z[64 * 68];   // fp32 z, [s][l] stride 68
    __shared__ __align__(16) float s_u[4608];      // union: phase1 staging | zh+zl bf16
    __shared__ __align__(16) float s_cbn[1024];
    __shared__ float s_rd1[128], s_rd2[128];
    __shared__ int   s_rk1[128], s_rk2[128];
    __shared__ int   s_ck[128];
    __shared__ float s_e[128];
    __shared__ int   s_ks[64];

    const int t  = threadIdx.x;
    const int b  = blockIdx.x >> 4;
    const int s0 = (blockIdx.x & 15) << 6;

    const unsigned short* cbh   = (const unsigned short*)(ws + 17408);
    const unsigned short* cbl   = cbh + 65536;
    const unsigned short* wouth = cbl + 65536;
    const unsigned short* woutl = wouth + 16384;

    // stage cbn -> LDS (256 f4)
    ((float4*)s_cbn)[t] = ((const float4*)(ws + 16384))[t];

    // ================= phase 1: z = W_in @ x_tile + b_in (fp32 VALU, exact) =================
    const int sgrp = t & 15;   // s quad
    const int lgrp = t >> 4;   // l quad (0..15)
    float accz[4][4];          // [a=l][i=s]
    #pragma unroll
    for (int a = 0; a < 4; a++) {
        float bi = b_in[lgrp * 4 + a];
        #pragma unroll
        for (int i = 0; i < 4; i++) accz[a][i] = bi;
    }
    float* s_w = s_u + 2048;   // [32][72]
    for (int cc = 0; cc < 8; cc++) {
        __syncthreads();
        #pragma unroll
        for (int it = 0; it < 2; it++) {
            int idx = it * 256 + t;      // 0..511
            int c = idx >> 4, sq = idx & 15;
            ((float4*)s_u)[c * 16 + sq] =
                ((const float4*)x)[(b * 256 + cc * 32 + c) * 256 + (s0 >> 2) + sq];
        }
        #pragma unroll
        for (int it = 0; it < 8; it++) {
            int idx = it * 256 + t;      // 0..2047
            int c = idx >> 6, l = idx & 63;
            s_w[c * 72 + l] = ws[(cc * 32 + c) * 64 + l];
        }
        __syncthreads();
        #pragma unroll 4
        for (int c = 0; c < 32; c++) {
            const float4 wv4 = *(const float4*)&s_w[c * 72 + lgrp * 4];
            const float4 xv4 = ((const float4*)s_u)[c * 16 + sgrp];
            const float wv[4] = {wv4.x, wv4.y, wv4.z, wv4.w};
            const float xv[4] = {xv4.x, xv4.y, xv4.z, xv4.w};
            #pragma unroll
            for (int a = 0; a < 4; a++)
                #pragma unroll
                for (int i = 0; i < 4; i++)
                    accz[a][i] = fmaf(wv[a], xv[i], accz[a][i]);
        }
    }
    __syncthreads();  // staging dead; reuse s_u for zh/zl

    unsigned short* zh = (unsigned short*)s_u;     // [64][72] bf16 hi
    unsigned short* zl = zh + 4608;                // [64][72] bf16 lo
    #pragma unroll
    for (int i = 0; i < 4; i++) {
        int s = sgrp * 4 + i;
        float4 zv;
        zv.x = accz[0][i]; zv.y = accz[1][i]; zv.z = accz[2][i]; zv.w = accz[3][i];
        *(float4*)&s_z[s * 68 + lgrp * 4] = zv;
        ushort4 hv, lv;
        hv.x = f2bf(zv.x); lv.x = f2bf(zv.x - bf2f(hv.x));
        hv.y = f2bf(zv.y); lv.y = f2bf(zv.y - bf2f(hv.y));
        hv.z = f2bf(zv.z); lv.z = f2bf(zv.z - bf2f(hv.z));
        hv.w = f2bf(zv.w); lv.w = f2bf(zv.w - bf2f(hv.w));
        *(ushort4*)&zh[s * 72 + lgrp * 4] = hv;
        *(ushort4*)&zl[s * 72 + lgrp * 4] = lv;
    }
    __syncthreads();

    // ================= phase 2: approx distances via bf16-split MFMA + top-2 =================
    const int w = t >> 6, lane = t & 63, quad = lane >> 4, n15 = lane & 15;
    const int p = w >> 1;     // position half (32 pos)
    const int ch = w & 1;     // code half (512 codes)

    short8v azh[2][2], azl[2][2];   // [mt][kh]
    #pragma unroll
    for (int mt = 0; mt < 2; mt++)
        #pragma unroll
        for (int kh = 0; kh < 2; kh++) {
            int s = p * 32 + mt * 16 + n15;
            azh[mt][kh] = *(const short8v*)&zh[s * 72 + kh * 32 + quad * 8];
            azl[mt][kh] = *(const short8v*)&zl[s * 72 + kh * 32 + quad * 8];
        }

    float d1[2][4], d2[2][4];
    int   k1[2][4], k2[2][4];
    #pragma unroll
    for (int mt = 0; mt < 2; mt++)
        #pragma unroll
        for (int r = 0; r < 4; r++) {
            d1[mt][r] = FLT_MAX; d2[mt][r] = FLT_MAX;
            k1[mt][r] = 0;       k2[mt][r] = 1;
        }

    for (int nt = 0; nt < 32; nt++) {
        const int krow = ch * 512 + nt * 16 + n15;
        const unsigned short* bhp = cbh + krow * 64 + quad * 8;
        const unsigned short* blp = cbl + krow * 64 + quad * 8;
        short8v bh0 = *(const short8v*)(bhp);
        short8v bh1 = *(const short8v*)(bhp + 32);
        short8v bl0 = *(const short8v*)(blp);
        short8v bl1 = *(const short8v*)(blp + 32);
        float cn = s_cbn[krow];
        #pragma unroll
        for (int mt = 0; mt < 2; mt++) {
            f32x4 acc = {0.f, 0.f, 0.f, 0.f};
            acc = MFMA16(azh[mt][0], bh0, acc);
            acc = MFMA16(azh[mt][1], bh1, acc);
            acc = MFMA16(azl[mt][0], bh0, acc);
            acc = MFMA16(azl[mt][1], bh1, acc);
            acc = MFMA16(azh[mt][0], bl0, acc);
            acc = MFMA16(azh[mt][1], bl1, acc);
            #pragma unroll
            for (int r = 0; r < 4; r++) {
                float d = fmaf(-2.f, acc[r], cn);
                bool lt1 = d < d1[mt][r];
                bool lt2 = d < d2[mt][r];
                d2[mt][r] = lt1 ? d1[mt][r] : (lt2 ? d : d2[mt][r]);
                k2[mt][r] = lt1 ? k1[mt][r] : (lt2 ? krow : k2[mt][r]);
                d1[mt][r] = lt1 ? d : d1[mt][r];
                k1[mt][r] = lt1 ? krow : k1[mt][r];
            }
        }
    }

    // reduce top-2 across the 16 lanes of each quad (lexicographic, lower k on tie)
    #pragma unroll
    for (int mt = 0; mt < 2; mt++)
        #pragma unroll
        for (int r = 0; r < 4; r++) {
            float a1 = d1[mt][r], a2 = d2[mt][r];
            int   b1 = k1[mt][r], b2 = k2[mt][r];
            #pragma unroll
            for (int m = 1; m < 16; m <<= 1) {
                float c1 = __shfl_xor(a1, m), c2 = __shfl_xor(a2, m);
                int   e1 = __shfl_xor(b1, m), e2 = __shfl_xor(b2, m);
                bool aLEc = (a1 < c1) || (a1 == c1 && b1 <= e1);
                float nd1 = aLEc ? a1 : c1;  int nk1 = aLEc ? b1 : e1;
                float xd  = aLEc ? c1 : a1;  int xk  = aLEc ? e1 : b1;
                float yd  = aLEc ? a2 : c2;  int yk  = aLEc ? b2 : e2;
                bool xLEy = (xd < yd) || (xd == yd && xk <= yk);
                a1 = nd1; b1 = nk1;
                a2 = xLEy ? xd : yd;  b2 = xLEy ? xk : yk;
            }
            if (n15 == 0) {
                int pos = p * 32 + mt * 16 + quad * 4 + r;
                s_rd1[pos * 2 + ch] = a1; s_rk1[pos * 2 + ch] = b1;
                s_rd2[pos * 2 + ch] = a2; s_rk2[pos * 2 + ch] = b2;
            }
        }
    __syncthreads();

    // merge the two code-halves -> top-2 candidates per position
    if (t < 64) {
        float a1 = s_rd1[t * 2],     a2 = s_rd2[t * 2];
        int   b1 = s_rk1[t * 2],     b2 = s_rk2[t * 2];
        float c1 = s_rd1[t * 2 + 1], c2 = s_rd2[t * 2 + 1];
        int   e1 = s_rk1[t * 2 + 1], e2 = s_rk2[t * 2 + 1];
        bool aLEc = (a1 < c1) || (a1 == c1 && b1 <= e1);
        float nd1 = aLEc ? a1 : c1;  int nk1 = aLEc ? b1 : e1;
        float xd  = aLEc ? c1 : a1;  int xk  = aLEc ? e1 : b1;
        float yd  = aLEc ? a2 : c2;  int yk  = aLEc ? b2 : e2;
        bool xLEy = (xd < yd) || (xd == yd && xk <= yk);
        s_ck[t * 2]     = nk1;
        s_ck[t * 2 + 1] = xLEy ? xk : yk;
    }
    __syncthreads();

    // exact fp32 recheck of both candidates
    if (t < 128) {
        int pos = t >> 1;
        int k = s_ck[t];
        const float4* cbr = (const float4*)(cb + k * 64);
        float dot = 0.f;
        #pragma unroll
        for (int i = 0; i < 16; i++) {
            float4 zv = *(const float4*)&s_z[pos * 68 + i * 4];
            float4 cv = cbr[i];
            dot = fmaf(zv.x, cv.x, dot);
            dot = fmaf(zv.y, cv.y, dot);
            dot = fmaf(zv.z, cv.z, dot);
            dot = fmaf(zv.w, cv.w, dot);
        }
        s_e[t] = fmaf(-2.f, dot, s_cbn[k]);
    }
    __syncthreads();
    if (t < 64) {
        float e1 = s_e[t * 2], e2 = s_e[t * 2 + 1];
        int   c1 = s_ck[t * 2], c2 = s_ck[t * 2 + 1];
        bool take1 = (e1 < e2) || (e1 == e2 && c1 <= c2);
        s_ks[t] = take1 ? c1 : c2;
    }
    __syncthreads();

    // ================= gather nearest = cb[idx] (exact fp32) =================
    {
        float4* nearest4 = (float4*)(out + 8388608);
        const float4* cb4 = (const float4*)cb;
        #pragma unroll
        for (int it = 0; it < 4; it++) {
            int idx = it * 256 + t;
            int s = idx >> 4, lq = idx & 15;
            nearest4[(b * 1024 + s0 + s) * 16 + lq] = cb4[s_ks[s] * 16 + lq];
        }
    }

    // ================= phase 3: out = W_out @ nearest + b_out (bf16-split MFMA) =================
    {
        short8v ah[4][2], al[4][2];   // [mt][kh]
        #pragma unroll
        for (int mt = 0; mt < 4; mt++) {
            int k = s_ks[mt * 16 + n15];
            #pragma unroll
            for (int kh = 0; kh < 2; kh++) {
                ah[mt][kh] = *(const short8v*)(cbh + k * 64 + kh * 32 + quad * 8);
                al[mt][kh] = *(const short8v*)(cbl + k * 64 + kh * 32 + quad * 8);
            }
        }
        #pragma unroll
        for (int nt = 0; nt < 4; nt++) {
            int c = w * 64 + nt * 16 + n15;
            const unsigned short* bhp = wouth + c * 64 + quad * 8;
            const unsigned short* blp = woutl + c * 64 + quad * 8;
            short8v bh0 = *(const short8v*)(bhp);
            short8v bh1 = *(const short8v*)(bhp + 32);
            short8v bl0 = *(const short8v*)(blp);
            short8v bl1 = *(const short8v*)(blp + 32);
            float bo = b_out[c];
            #pragma unroll
            for (int mt = 0; mt < 4; mt++) {
                f32x4 acc = {0.f, 0.f, 0.f, 0.f};
                acc = MFMA16(ah[mt][0], bh0, acc);
                acc = MFMA16(ah[mt][1], bh1, acc);
                acc = MFMA16(al[mt][0], bh0, acc);
                acc = MFMA16(al[mt][1], bh1, acc);
                acc = MFMA16(ah[mt][0], bl0, acc);
                acc = MFMA16(ah[mt][1], bl1, acc);
                float4 o;
                o.x = acc[0] + bo; o.y = acc[1] + bo; o.z = acc[2] + bo; o.w = acc[3] + bo;
                *(float4*)&out[(b * 256 + c) * 1024 + s0 + mt * 16 + quad * 4] = o;
            }
        }
    }
}

extern "C" void kernel_launch(void* const* d_in, const int* in_sizes, int n_in,
                              void* d_out, int out_size, void* d_ws, size_t ws_size,
                              hipStream_t stream) {
    const float* x    = (const float*)d_in[0];
    const float* cb   = (const float*)d_in[1];
    const float* Win  = (const float*)d_in[2];
    const float* bin  = (const float*)d_in[3];
    const float* Wout = (const float*)d_in[4];
    const float* bout = (const float*)d_in[5];
    float* out = (float*)d_out;
    float* ws  = (float*)d_ws;

    prep_kernel<<<324, 256, 0, stream>>>(Win, Wout, cb, ws);
    vq_kernel<<<512, 256, 0, stream>>>(x, cb, bin, bout, ws, out);
}